// Round 8
// baseline (378.074 us; speedup 1.0000x reference)
//
#include <hip/hip_runtime.h>

#define FG_THRESH 0.7f
#define BG_HI 0.5f
#define BG_LO 0.1f
#define BATCH 256
#define FG_ROIS 128
#define KGT 256
#define CLS 81
#define CPT 5                      // mask words per thread (covers NCH<=1280)
#define NCHPAD 1280
#define REPS 8                     // measurement round: 8x idempotent repeat

typedef unsigned long long ull;

// ---------------------------------------------------------------------------
// A: IoU max/argmax. One roi per lane; wave pair splits k-range (0..127 /
//    128..255), merge tie -> lower half (= lower k) => exact np first-of-max.
//    gsh[k] is a wave-uniform broadcast read (1 ds_read_b128 per k per wave).
//    Division filter: inter > best*denom*0.999999f is provably conservative
//    (margin 1e-6 >> 3ulp), so the IEEE div runs exactly on true candidates.
// ---------------------------------------------------------------------------
__global__ __launch_bounds__(256) void k_iou(
    const float* __restrict__ proposals,   // (N,4)
    const float* __restrict__ gt_boxes,    // (K,4)
    int N, int M, int NCH,
    int* __restrict__ gt_assign,           // [M]
    ull* __restrict__ fgm,                 // [NCH]
    ull* __restrict__ bgm,                 // [NCH]
    ull* __restrict__ nbm)                 // [NCH]
{
    __shared__ float4 gsh[KGT];
    __shared__ float sbest[2][64];
    __shared__ int   sbk[2][64];

    int tid = threadIdx.x;
    gsh[tid] = ((const float4*)gt_boxes)[tid];
    __syncthreads();

    int lane = tid & 63, wv = tid >> 6;
    int pair = wv >> 1;                    // which chunk of this block (0/1)
    int half = wv & 1;                     // which k half
    int ch = blockIdx.x * 2 + pair;
    int roi = ch * 64 + lane;
    bool isv = (ch < NCH) && (roi < M);    // all-true for this shape (M = NCH*64)

    float4 a;
    if (isv) a = (roi < N) ? ((const float4*)proposals)[roi] : gsh[roi - N];
    else     a = gsh[0];
    float area_a = (a.z - a.x + 1.0f) * (a.w - a.y + 1.0f);

    for (int rep = 0; rep < REPS; ++rep) {
        asm volatile("" ::: "memory");

        float best = -1.0f;
        int bestk = 0;
        int k0 = half * 128;
        #pragma unroll 8
        for (int kk = 0; kk < 128; ++kk) {
            int k = k0 + kk;
            float4 g = gsh[k];
            float gar = (g.z - g.x + 1.0f) * (g.w - g.y + 1.0f);
            float x1 = fmaxf(a.x, g.x);
            float y1 = fmaxf(a.y, g.y);
            float x2 = fminf(a.z, g.z);
            float y2 = fminf(a.w, g.w);
            float iw = fmaxf(x2 - x1 + 1.0f, 0.0f);
            float ih = fmaxf(y2 - y1 + 1.0f, 0.0f);
            float inter = iw * ih;
            float denom = area_a + gar - inter;        // > 0 always
            if (inter > best * denom * 0.999999f) {    // conservative filter
                float q = inter / denom;               // IEEE div = np
                if (q > best) { best = q; bestk = k; } // strict > keeps first
            }
        }

        if (half == 0) { sbest[pair][lane] = best; sbk[pair][lane] = bestk; }
        __syncthreads();
        if (half == 1) {
            float ab = sbest[pair][lane];
            int   ak = sbk[pair][lane];
            if (!(best > ab)) { best = ab; bestk = ak; }   // tie -> lower k half
            bool fgp = isv && (best >= FG_THRESH);
            bool bgp = isv && (best < BG_HI) && (best >= BG_LO);
            bool nbp = isv && !bgp;
            if (isv) gt_assign[roi] = bestk;               // coalesced
            ull mf = __ballot(fgp);                        // wave == 64-roi chunk
            ull mb = __ballot(bgp);
            ull mn = __ballot(nbp);
            if (lane == 0 && ch < NCH) { fgm[ch] = mf; bgm[ch] = mb; nbm[ch] = mn; }
        }
        __syncthreads();
    }
}

// ---------------------------------------------------------------------------
// B: 81 blocks, scratch-free. Stage masks to LDS; popcount/scan/extract read
//    LDS directly (no per-thread arrays -> no scratch demotion). Meta via
//    ballot one-hot argmax; outputs computed, not gathered.
// ---------------------------------------------------------------------------
__global__ __launch_bounds__(256) void k_finish(
    const float* __restrict__ proposals,
    const float* __restrict__ gt_boxes,
    const float* __restrict__ gt_labels,   // (K,C) one-hot rows
    int N, int NCH,
    const int* __restrict__ gt_assign,
    const ull* __restrict__ fgm,
    const ull* __restrict__ bgm,
    const ull* __restrict__ nbm,
    float* __restrict__ out_rois,          // (BATCH,4)
    float* __restrict__ out_labels,        // (BATCH*CLS)
    float4* __restrict__ out_bbox)         // (BATCH*CLS) float4 slots
{
    __shared__ ull sf[NCHPAD], sb[NCHPAD], sn[NCHPAD];
    __shared__ int fgl[FG_ROIS], bgl[BATCH], nbl[BATCH];
    __shared__ int wtot[3][4];
    __shared__ int lm_cls[8];
    __shared__ float4 lm_t[8];

    int tid = threadIdx.x;
    int lane = tid & 63, wv = tid >> 6;

    for (int rep = 0; rep < REPS; ++rep) {
        asm volatile("" ::: "memory");

        for (int idx = tid; idx < NCHPAD; idx += 256) {
            bool v = (idx < NCH);
            sf[idx] = v ? fgm[idx] : 0ull;
            sb[idx] = v ? bgm[idx] : 0ull;
            sn[idx] = v ? nbm[idx] : 0ull;
        }
        __syncthreads();

        int lo = tid * CPT;
        int pc0 = 0, pc1 = 0, pc2 = 0;
        #pragma unroll
        for (int r = 0; r < CPT; ++r) {
            pc0 += __popcll(sf[lo + r]);
            pc1 += __popcll(sb[lo + r]);
            pc2 += __popcll(sn[lo + r]);
        }

        int i0 = pc0, i1 = pc1, i2 = pc2;
        #pragma unroll
        for (int d = 1; d < 64; d <<= 1) {
            int t0 = __shfl_up(i0, d);
            int t1 = __shfl_up(i1, d);
            int t2 = __shfl_up(i2, d);
            if (lane >= d) { i0 += t0; i1 += t1; i2 += t2; }
        }
        if (lane == 63) { wtot[0][wv] = i0; wtot[1][wv] = i1; wtot[2][wv] = i2; }
        __syncthreads();
        int o0 = 0, o1 = 0, o2 = 0;
        for (int x = 0; x < wv; ++x) { o0 += wtot[0][x]; o1 += wtot[1][x]; o2 += wtot[2][x]; }
        int b0 = o0 + i0 - pc0;
        int b1 = o1 + i1 - pc1;
        int b2 = o2 + i2 - pc2;
        int num_fg = wtot[0][0] + wtot[0][1] + wtot[0][2] + wtot[0][3];
        int num_bg = wtot[1][0] + wtot[1][1] + wtot[1][2] + wtot[1][3];

        // ordered extraction straight from LDS (scalar registers only)
        #pragma unroll
        for (int r = 0; r < CPT; ++r) {
            int w = lo + r;
            if (b0 < FG_ROIS) {
                ull m = sf[w];
                while (m && b0 < FG_ROIS) { fgl[b0++] = (w << 6) + __ffsll(m) - 1; m &= m - 1; }
            }
            if (b1 < BATCH) {
                ull m = sb[w];
                while (m && b1 < BATCH)   { bgl[b1++] = (w << 6) + __ffsll(m) - 1; m &= m - 1; }
            }
            if (b2 < BATCH) {
                ull m = sn[w];
                while (m && b2 < BATCH)   { nbl[b2++] = (w << 6) + __ffsll(m) - 1; m &= m - 1; }
            }
        }
        __syncthreads();

        int fg_take = min(FG_ROIS, num_fg);
        int eBase = blockIdx.x * 256;
        int posLo = eBase / CLS;
        int posHi = (eBase + 255) / CLS;
        int np = posHi - posLo + 1;            // <= 5

        for (int s = wv; s < np; s += 4) {
            int pos = posLo + s;
            int is_fg = (pos < fg_take) ? 1 : 0;
            int j = pos - fg_take;
            int keep = is_fg ? fgl[pos] : ((j < num_bg) ? bgl[j] : nbl[j - num_bg]);
            float4 a = (keep < N) ? ((const float4*)proposals)[keep]
                                  : ((const float4*)gt_boxes)[keep - N];
            int ga = gt_assign[keep];
            float4 g = ((const float4*)gt_boxes)[ga];

            float ew = a.z - a.x + 1.0f, eh = a.w - a.y + 1.0f;
            float ecx = a.x + 0.5f * ew, ecy = a.y + 0.5f * eh;
            float gw = g.z - g.x + 1.0f, gh = g.w - g.y + 1.0f;
            float gcx = g.x + 0.5f * gw, gcy = g.y + 0.5f * gh;

            int cls = 0;
            if (is_fg) {
                float l1 = gt_labels[(size_t)ga * CLS + lane];
                int c2 = lane + 64;
                float l2 = (c2 < CLS) ? gt_labels[(size_t)ga * CLS + c2] : 0.0f;
                ull m1 = __ballot(l1 > 0.5f);
                ull m2 = __ballot(c2 < CLS && l2 > 0.5f);
                cls = m1 ? (__ffsll(m1) - 1) : (m2 ? 64 + __ffsll(m2) - 1 : 0);
            }
            if (lane == 0) {
                lm_cls[s] = cls;
                lm_t[s] = make_float4((gcx - ecx) / ew, (gcy - ecy) / eh,
                                      logf(gw / ew), logf(gh / eh));
            }
        }

        if (blockIdx.x == 0) {
            int pos = tid;
            int is_fg = (pos < fg_take) ? 1 : 0;
            int j = pos - fg_take;
            int keep = is_fg ? fgl[pos] : ((j < num_bg) ? bgl[j] : nbl[j - num_bg]);
            float4 a = (keep < N) ? ((const float4*)proposals)[keep]
                                  : ((const float4*)gt_boxes)[keep - N];
            ((float4*)out_rois)[pos] = a;
        }
        __syncthreads();

        int e = eBase + tid;
        int pos = e / CLS, cc = e - pos * CLS;
        int li = pos - posLo;
        int cl = lm_cls[li];
        out_labels[e] = (cc == cl) ? 1.0f : 0.0f;
        out_bbox[e] = (cl > 0 && cc == cl) ? lm_t[li]
                                           : make_float4(0.f, 0.f, 0.f, 0.f);
        __syncthreads();
    }
}

// ---------------------------------------------------------------------------
extern "C" void kernel_launch(void* const* d_in, const int* in_sizes, int n_in,
                              void* d_out, int out_size, void* d_ws, size_t ws_size,
                              hipStream_t stream)
{
    const float* proposals = (const float*)d_in[0];
    const float* gt_labels = (const float*)d_in[1];
    const float* gt_boxes  = (const float*)d_in[2];
    int N = in_sizes[0] / 4;           // 80000
    int K = in_sizes[2] / 4;           // 256
    int M = N + K;                     // 80256
    int NCH = (M + 63) / 64;           // 1254

    char* ws = (char*)d_ws;
    size_t off = 0;
    auto alloc = [&](size_t bytes) -> void* {
        void* p = ws + off;
        off += (bytes + 255) & ~(size_t)255;
        return p;
    };
    int* gt_assign = (int*)alloc((size_t)M * 4);
    ull* fgm = (ull*)alloc((size_t)NCH * 8);
    ull* bgm = (ull*)alloc((size_t)NCH * 8);
    ull* nbm = (ull*)alloc((size_t)NCH * 8);

    float* out_rois   = (float*)d_out;
    float* out_labels = out_rois + BATCH * 4;
    float4* out_bbox  = (float4*)(out_labels + BATCH * CLS);

    int nb1 = (NCH + 1) / 2;           // 627 blocks, 2 chunks each
    k_iou<<<nb1, 256, 0, stream>>>(proposals, gt_boxes, N, M, NCH,
                                   gt_assign, fgm, bgm, nbm);
    int nb2 = (BATCH * CLS) / 256;     // 81 exact
    k_finish<<<nb2, 256, 0, stream>>>(proposals, gt_boxes, gt_labels, N, NCH,
                                      gt_assign, fgm, bgm, nbm,
                                      out_rois, out_labels, out_bbox);
    (void)K; (void)n_in; (void)out_size; (void)ws_size;
}

// Round 9
// 33.820 us; speedup vs baseline: 11.1791x; 11.1791x over previous
//
#include <hip/hip_runtime.h>

#define FG_THRESH 0.7f
#define BG_HI 0.5f
#define BG_LO 0.1f
#define BATCH 256
#define FG_ROIS 128
#define KGT 256
#define CLS 81
#define CPT 5                      // mask words per thread (covers NCH<=1280)
#define NCHPAD 1280

typedef unsigned long long ull;

// ---------------------------------------------------------------------------
// A: IoU max/argmax (r7's 16us structure: 4 lanes per roi, k = c mod 4,
//    garea staged in LDS) + margin-filtered exact division:
//    skip k when inter <= best*denom*0.999999f  =>  inter/denom < best(1-8e-7)
//    =>  RN(q) < best, so skipping is bit-exact; div runs only on candidates.
// ---------------------------------------------------------------------------
__global__ __launch_bounds__(256) void k_iou(
    const float* __restrict__ proposals,   // (N,4)
    const float* __restrict__ gt_boxes,    // (K,4)
    int N, int M,
    int* __restrict__ gt_assign,           // [M]
    ull* __restrict__ fgm,                 // [NCH]
    ull* __restrict__ bgm,                 // [NCH]
    ull* __restrict__ nbm)                 // [NCH]
{
    __shared__ float4 gsh[KGT];
    __shared__ float garea[KGT];
    __shared__ unsigned int wm[3][4];

    int tid = threadIdx.x;
    {
        float4 g = ((const float4*)gt_boxes)[tid];
        gsh[tid] = g;
        garea[tid] = (g.z - g.x + 1.0f) * (g.w - g.y + 1.0f);
    }
    __syncthreads();

    int wv = tid >> 6, lane = tid & 63;
    int c = lane & 3;          // k-class (k mod 4)
    int rj = lane >> 2;        // roi within wave, 0..15
    int roi = blockIdx.x * 64 + wv * 16 + rj;

    float best = -1.0f;
    int bestk = 0;
    {
        float4 a;
        if (roi < M) a = (roi < N) ? ((const float4*)proposals)[roi]
                                   : gsh[roi - N];
        else         a = gsh[0];               // dummy, masked below
        float area_a = (a.z - a.x + 1.0f) * (a.w - a.y + 1.0f);
        #pragma unroll 4
        for (int j = 0; j < KGT / 4; ++j) {
            int k = (j << 2) | c;
            float4 g = gsh[k];
            float x1 = fmaxf(a.x, g.x);
            float y1 = fmaxf(a.y, g.y);
            float x2 = fminf(a.z, g.z);
            float y2 = fminf(a.w, g.w);
            float iw = fmaxf(x2 - x1 + 1.0f, 0.0f);
            float ih = fmaxf(y2 - y1 + 1.0f, 0.0f);
            float inter = iw * ih;
            float denom = area_a + garea[k] - inter;       // > 0 always
            if (inter > best * denom * 0.999999f) {        // conservative filter
                float q = inter / denom;                   // IEEE div = np
                if (q > best) { best = q; bestk = k; }     // strict > keeps first
            }
        }
    }
    #pragma unroll
    for (int d = 1; d < 4; d <<= 1) {
        float ob = __shfl_xor(best, d);
        int   kb = __shfl_xor(bestk, d);
        if (ob > best || (ob == best && kb < bestk)) { best = ob; bestk = kb; }
    }
    float bset = __shfl(best, (lane & 15) * 4);
    int   bk   = __shfl(bestk, (lane & 15) * 4);

    int roi2 = blockIdx.x * 64 + wv * 16 + (lane & 15);
    bool isv = (lane < 16) && (roi2 < M);
    bool fgp = isv && (bset >= FG_THRESH);
    bool bgp = isv && (bset < BG_HI) && (bset >= BG_LO);
    bool nbp = isv && !bgp;
    if (isv) gt_assign[roi2] = bk;

    unsigned int mf = (unsigned int)(__ballot(fgp) & 0xFFFFull);
    unsigned int mb = (unsigned int)(__ballot(bgp) & 0xFFFFull);
    unsigned int mn = (unsigned int)(__ballot(nbp) & 0xFFFFull);
    if (lane == 0) { wm[0][wv] = mf; wm[1][wv] = mb; wm[2][wv] = mn; }
    __syncthreads();
    if (tid == 0) {
        fgm[blockIdx.x] = (ull)wm[0][0] | ((ull)wm[0][1] << 16) | ((ull)wm[0][2] << 32) | ((ull)wm[0][3] << 48);
        bgm[blockIdx.x] = (ull)wm[1][0] | ((ull)wm[1][1] << 16) | ((ull)wm[1][2] << 32) | ((ull)wm[1][3] << 48);
        nbm[blockIdx.x] = (ull)wm[2][0] | ((ull)wm[2][1] << 16) | ((ull)wm[2][2] << 32) | ((ull)wm[2][3] << 48);
    }
}

// ---------------------------------------------------------------------------
// B: 81 blocks. Stage masks -> per-WORD exclusive prefixes (thread scan +
//    serial-5 store) -> PARALLEL rank-scatter extraction (word-per-lane,
//    direct-addressed ranks, cap-skip) -> meta (ballot one-hot argmax) ->
//    computed outputs. Block 0 writes rois.
// ---------------------------------------------------------------------------
__global__ __launch_bounds__(256) void k_finish(
    const float* __restrict__ proposals,
    const float* __restrict__ gt_boxes,
    const float* __restrict__ gt_labels,   // (K,C) one-hot rows
    int N, int NCH,
    const int* __restrict__ gt_assign,
    const ull* __restrict__ fgm,
    const ull* __restrict__ bgm,
    const ull* __restrict__ nbm,
    float* __restrict__ out_rois,          // (BATCH,4)
    float* __restrict__ out_labels,        // (BATCH*CLS)
    float4* __restrict__ out_bbox)         // (BATCH*CLS) float4 slots
{
    __shared__ ull sf[NCHPAD], sb[NCHPAD], sn[NCHPAD];     // 30 KB
    __shared__ int pf[NCHPAD], pb[NCHPAD], pn[NCHPAD];     // 15 KB word prefixes
    __shared__ int fgl[FG_ROIS], bgl[BATCH], nbl[BATCH];
    __shared__ int wtot[3][4];
    __shared__ int lm_cls[8];
    __shared__ float4 lm_t[8];

    int tid = threadIdx.x;
    int lane = tid & 63, wv = tid >> 6;

    // coalesced staging (pad words zeroed)
    for (int idx = tid; idx < NCHPAD; idx += 256) {
        bool v = (idx < NCH);
        sf[idx] = v ? fgm[idx] : 0ull;
        sb[idx] = v ? bgm[idx] : 0ull;
        sn[idx] = v ? nbm[idx] : 0ull;
    }
    __syncthreads();

    int lo = tid * CPT;
    int pc0 = 0, pc1 = 0, pc2 = 0;
    #pragma unroll
    for (int r = 0; r < CPT; ++r) {
        pc0 += __popcll(sf[lo + r]);
        pc1 += __popcll(sb[lo + r]);
        pc2 += __popcll(sn[lo + r]);
    }

    // wave inclusive scan, then cross-wave offsets
    int i0 = pc0, i1 = pc1, i2 = pc2;
    #pragma unroll
    for (int d = 1; d < 64; d <<= 1) {
        int t0 = __shfl_up(i0, d);
        int t1 = __shfl_up(i1, d);
        int t2 = __shfl_up(i2, d);
        if (lane >= d) { i0 += t0; i1 += t1; i2 += t2; }
    }
    if (lane == 63) { wtot[0][wv] = i0; wtot[1][wv] = i1; wtot[2][wv] = i2; }
    __syncthreads();
    int o0 = 0, o1 = 0, o2 = 0;
    for (int x = 0; x < wv; ++x) { o0 += wtot[0][x]; o1 += wtot[1][x]; o2 += wtot[2][x]; }
    int b0 = o0 + i0 - pc0;      // thread-exclusive prefixes
    int b1 = o1 + i1 - pc1;
    int b2 = o2 + i2 - pc2;
    int num_fg = wtot[0][0] + wtot[0][1] + wtot[0][2] + wtot[0][3];
    int num_bg = wtot[1][0] + wtot[1][1] + wtot[1][2] + wtot[1][3];

    // per-WORD exclusive prefixes
    #pragma unroll
    for (int r = 0; r < CPT; ++r) {
        int w = lo + r;
        pf[w] = b0; b0 += __popcll(sf[w]);
        pb[w] = b1; b1 += __popcll(sb[w]);
        pn[w] = b2; b2 += __popcll(sn[w]);
    }
    __syncthreads();

    // parallel rank-scatter: word-per-lane passes, cap-skip whole words
    #pragma unroll
    for (int pass = 0; pass < CPT; ++pass) {
        int w = tid + 256 * pass;
        int base = pf[w];
        if (base < FG_ROIS) {
            ull m = sf[w];
            while (m) {
                if (base >= FG_ROIS) break;
                fgl[base++] = (w << 6) + __ffsll(m) - 1;
                m &= m - 1;
            }
        }
        base = pb[w];
        if (base < BATCH) {
            ull m = sb[w];
            while (m) {
                if (base >= BATCH) break;
                bgl[base++] = (w << 6) + __ffsll(m) - 1;
                m &= m - 1;
            }
        }
        base = pn[w];
        if (base < BATCH) {
            ull m = sn[w];
            while (m) {
                if (base >= BATCH) break;
                nbl[base++] = (w << 6) + __ffsll(m) - 1;
                m &= m - 1;
            }
        }
    }
    __syncthreads();

    int fg_take = min(FG_ROIS, num_fg);
    int eBase = blockIdx.x * 256;
    int posLo = eBase / CLS;
    int posHi = (eBase + 255) / CLS;
    int np = posHi - posLo + 1;            // <= 5

    // per-slot meta: wave wv handles slots wv, wv+4 (all lanes cooperate)
    for (int s = wv; s < np; s += 4) {
        int pos = posLo + s;
        int is_fg = (pos < fg_take) ? 1 : 0;
        int j = pos - fg_take;
        int keep = is_fg ? fgl[pos] : ((j < num_bg) ? bgl[j] : nbl[j - num_bg]);
        float4 a = (keep < N) ? ((const float4*)proposals)[keep]
                              : ((const float4*)gt_boxes)[keep - N];
        int ga = gt_assign[keep];
        float4 g = ((const float4*)gt_boxes)[ga];

        float ew = a.z - a.x + 1.0f, eh = a.w - a.y + 1.0f;
        float ecx = a.x + 0.5f * ew, ecy = a.y + 0.5f * eh;
        float gw = g.z - g.x + 1.0f, gh = g.w - g.y + 1.0f;
        float gcx = g.x + 0.5f * gw, gcy = g.y + 0.5f * gh;

        int cls = 0;
        if (is_fg) {
            float l1 = gt_labels[(size_t)ga * CLS + lane];
            int c2 = lane + 64;
            float l2 = (c2 < CLS) ? gt_labels[(size_t)ga * CLS + c2] : 0.0f;
            ull m1 = __ballot(l1 > 0.5f);
            ull m2 = __ballot(c2 < CLS && l2 > 0.5f);
            cls = m1 ? (__ffsll(m1) - 1) : (m2 ? 64 + __ffsll(m2) - 1 : 0);
        }
        if (lane == 0) {
            lm_cls[s] = cls;
            lm_t[s] = make_float4((gcx - ecx) / ew, (gcy - ecy) / eh,
                                  logf(gw / ew), logf(gh / eh));
        }
    }

    if (blockIdx.x == 0) {
        int pos = tid;
        int is_fg = (pos < fg_take) ? 1 : 0;
        int j = pos - fg_take;
        int keep = is_fg ? fgl[pos] : ((j < num_bg) ? bgl[j] : nbl[j - num_bg]);
        float4 a = (keep < N) ? ((const float4*)proposals)[keep]
                              : ((const float4*)gt_boxes)[keep - N];
        ((float4*)out_rois)[pos] = a;
    }
    __syncthreads();

    int e = eBase + tid;
    int pos = e / CLS, cc = e - pos * CLS;
    int li = pos - posLo;
    int cl = lm_cls[li];
    out_labels[e] = (cc == cl) ? 1.0f : 0.0f;
    out_bbox[e] = (cl > 0 && cc == cl) ? lm_t[li]
                                       : make_float4(0.f, 0.f, 0.f, 0.f);
}

// ---------------------------------------------------------------------------
extern "C" void kernel_launch(void* const* d_in, const int* in_sizes, int n_in,
                              void* d_out, int out_size, void* d_ws, size_t ws_size,
                              hipStream_t stream)
{
    const float* proposals = (const float*)d_in[0];
    const float* gt_labels = (const float*)d_in[1];
    const float* gt_boxes  = (const float*)d_in[2];
    int N = in_sizes[0] / 4;           // 80000
    int K = in_sizes[2] / 4;           // 256
    int M = N + K;                     // 80256
    int NCH = (M + 63) / 64;           // 1254

    char* ws = (char*)d_ws;
    size_t off = 0;
    auto alloc = [&](size_t bytes) -> void* {
        void* p = ws + off;
        off += (bytes + 255) & ~(size_t)255;
        return p;
    };
    int* gt_assign = (int*)alloc((size_t)M * 4);
    ull* fgm = (ull*)alloc((size_t)NCH * 8);
    ull* bgm = (ull*)alloc((size_t)NCH * 8);
    ull* nbm = (ull*)alloc((size_t)NCH * 8);

    float* out_rois   = (float*)d_out;
    float* out_labels = out_rois + BATCH * 4;
    float4* out_bbox  = (float4*)(out_labels + BATCH * CLS);

    k_iou<<<NCH, 256, 0, stream>>>(proposals, gt_boxes, N, M,
                                   gt_assign, fgm, bgm, nbm);
    int nb2 = (BATCH * CLS) / 256;     // 81 exact
    k_finish<<<nb2, 256, 0, stream>>>(proposals, gt_boxes, gt_labels, N, NCH,
                                      gt_assign, fgm, bgm, nbm,
                                      out_rois, out_labels, out_bbox);
    (void)K; (void)n_in; (void)out_size; (void)ws_size;
}